// Round 5
// baseline (225.255 us; speedup 1.0000x reference)
//
#include <hip/hip_runtime.h>

// Dims fixed by the problem: B=64, C=8, N=512, E=512, H=8, dh=64
// logits out: [B, C*N] = 262144 floats at d_out[0]
// Q3 out:     [B, C, E] = 262144 floats at d_out[262144]

typedef _Float16 f16x8 __attribute__((ext_vector_type(8)));
typedef float f32x4 __attribute__((ext_vector_type(4)));

__device__ __forceinline__ void async16(const void* g, void* l) {
  __builtin_amdgcn_global_load_lds(
      (const __attribute__((address_space(1))) unsigned int*)g,
      (__attribute__((address_space(3))) unsigned int*)l, 16, 0, 0);
}

// ---------------- prep: colsum(Wk2) + convert Wk1/Wv to f16 ----------------
__global__ __launch_bounds__(256) void prep_w(const float* __restrict__ Wk1,
                                              const float* __restrict__ Wv,
                                              const float* __restrict__ Wk2,
                                              _Float16* __restrict__ W1h,
                                              _Float16* __restrict__ W2h,
                                              float* __restrict__ colsum) {
  const int bid = blockIdx.x;
  if (bid < 16) {
    const int tx = threadIdx.x & 31, ty = threadIdx.x >> 5;
    const int col = bid * 32 + tx;
    float s = 0.f;
#pragma unroll 4
    for (int e = ty * 64; e < ty * 64 + 64; ++e) s += Wk2[e * 512 + col];
    __shared__ float red[8][32];
    red[ty][tx] = s;
    __syncthreads();
    if (ty == 0) {
      float t = 0.f;
#pragma unroll
      for (int g = 0; g < 8; ++g) t += red[g][tx];
      colsum[col] = t;
    }
  } else {
    const int cb = bid - 16;
    const float* src = (cb < 128) ? Wk1 : Wv;
    _Float16* dst = (cb < 128) ? W1h : W2h;
    const size_t off = (size_t)(cb & 127) * 2048 + threadIdx.x * 8;
    float4 a = *(const float4*)(src + off);
    float4 b = *(const float4*)(src + off + 4);
    union { _Float16 h[8]; uint4 u; } pk;
    pk.h[0] = (_Float16)a.x; pk.h[1] = (_Float16)a.y;
    pk.h[2] = (_Float16)a.z; pk.h[3] = (_Float16)a.w;
    pk.h[4] = (_Float16)b.x; pk.h[5] = (_Float16)b.y;
    pk.h[6] = (_Float16)b.z; pk.h[7] = (_Float16)b.w;
    *(uint4*)(dst + off) = pk.u;
  }
}

// ---------------- Q1 = [ge | sc] @ [Wqf | Wqs].T  (K=1026) -----------------
__global__ __launch_bounds__(256) void q1_mfma_kernel(
    const float* __restrict__ ge, const float* __restrict__ sc,
    const float* __restrict__ Wqf, const float* __restrict__ Wqs,
    float* __restrict__ Q1) {
  const int mb = blockIdx.x, nb = blockIdx.y, ks = blockIdx.z;
  const int tid = threadIdx.x;
  const int lane = tid & 63, wave = tid >> 6;
  const int wm = (wave >> 1) * 32, wn = (wave & 1) * 32;

  __shared__ __align__(16) _Float16 As[64][40];
  __shared__ __align__(16) _Float16 Ws[64][40];

  f32x4 acc[2][2] = {};
  const int qd = (lane >> 4) * 8, rr = lane & 15;

  for (int kt = 0; kt < 9; ++kt) {
    const int kb = ks * 288 + kt * 32;
#pragma unroll
    for (int f0 = 0; f0 < 2; ++f0) {
      int f = tid + f0 * 256;
      int r = f >> 3, c4 = (f & 7) * 4;
      int m = mb * 64 + r;
      int e = nb * 64 + r;
#pragma unroll
      for (int j = 0; j < 4; ++j) {
        int k = kb + c4 + j;
        float a = 0.f, w = 0.f;
        if (k < 512) {
          a = ge[(m >> 3) * 512 + k];
          w = Wqf[(size_t)e * 512 + k];
        } else if (k < 1026) {
          a = sc[(size_t)m * 514 + (k - 512)];
          w = Wqs[(size_t)e * 514 + (k - 512)];
        }
        As[r][c4 + j] = (_Float16)a;
        Ws[r][c4 + j] = (_Float16)w;
      }
    }
    __syncthreads();
    f16x8 af[2], bfr[2];
#pragma unroll
    for (int mi = 0; mi < 2; ++mi) af[mi] = *(const f16x8*)&As[wm + mi * 16 + rr][qd];
#pragma unroll
    for (int ni = 0; ni < 2; ++ni) bfr[ni] = *(const f16x8*)&Ws[wn + ni * 16 + rr][qd];
#pragma unroll
    for (int mi = 0; mi < 2; ++mi)
#pragma unroll
      for (int ni = 0; ni < 2; ++ni)
        acc[mi][ni] =
            __builtin_amdgcn_mfma_f32_16x16x32_f16(af[mi], bfr[ni], acc[mi][ni], 0, 0, 0);
    __syncthreads();
  }

  const int col = lane & 15, rq = (lane >> 4) * 4;
#pragma unroll
  for (int mi = 0; mi < 2; ++mi)
#pragma unroll
    for (int ni = 0; ni < 2; ++ni)
#pragma unroll
      for (int r = 0; r < 4; ++r) {
        int m = mb * 64 + wm + mi * 16 + rq + r;
        int e = nb * 64 + wn + ni * 16 + col;
        atomicAdd(&Q1[(size_t)m * 512 + e], acc[mi][ni][r]);
      }
}

// ---------------- K1 / V GEMM, split passes + fused k2sum ------------------
// R11 (resubmit after infra failure): the dual-accumulator block (128 accum
// VGPRs -> 256 regs/wave -> 8 waves/CU, 2-phase ceiling ~540 TF) is split
// into two single-GEMM passes sharing the staged A tile via L2 (m97
// geometry: 128x128 tile, BK=64, single-W double-buffer, 3 blocks/CU, 12
// waves/CU). work = mb*8 + pass*4 + nb; XCD-chunked swizzle keeps all 8
// siblings of an mb adjacent on one XCD so the second pass's A read is an
// L2 hit. pass0 = K1 (+k2sum on nb==0); pass1 = V with LDS-transposed
// 256B stores.
__global__ __launch_bounds__(256, 3) void gemm_kv(
    const float* __restrict__ A, const _Float16* __restrict__ W1,
    const _Float16* __restrict__ W2, const float* __restrict__ colsum,
    _Float16* __restrict__ K1, _Float16* __restrict__ Vt,
    float* __restrict__ k2sum) {
  const int flat = (int)blockIdx.x;                 // 0..2047
  const int work = (flat & 7) * 256 + (flat >> 3);  // bijective, 2048%8==0
  const int mb = work >> 3;                         // 0..255
  const int pass = (work >> 2) & 1;                 // 0=K1, 1=V
  const int nb = work & 3;
  const bool do_k2 = (work & 7) == 0;               // pass0, nb0
  const int tid = threadIdx.x, lane = tid & 63, wave = tid >> 6;
  const int wm = (wave >> 1) * 64, wn = (wave & 1) * 64;
  const int row0 = mb * 128, col0 = nb * 128;
  const int b = mb >> 2;

  // 48 KB: Ah = S[0..8192) (16 KB f16, swizzled), W dbuf = S[8192..24576).
  // pass1 epilogue reuses S[0..16384) as the 32 KB transpose tile.
  __shared__ __align__(16) _Float16 S[24576];
  _Float16* Ah = S;
  _Float16* Wb = S + 8192;  // [2][128*64]

  const _Float16* W = pass ? W2 : W1;

  f32x4 acc[4][4] = {};
  float k2p[4] = {0.f, 0.f, 0.f, 0.f};
  const int q = lane >> 4, rr = lane & 15;
  const int wlr = lane >> 3, wlc = lane & 7;
  const int cswz = wlc ^ wlr;  // W chunk swizzle (8 chunks of 8 f16 per row)

  // A staging geometry: thread owns rows ar0+32j (j=0..3), 8-half chunk ac.
  const int ar0 = tid >> 3, ac = tid & 7;
  const float* aptr = A + (size_t)(row0 + ar0) * 512 + ac * 8;
  const int aslot = ac ^ (ar0 & 7);

  float4 areg[4][2];
  float4 cs0, cs1;

  auto issue_a = [&](int kt) {
#pragma unroll
    for (int j = 0; j < 4; ++j) {
      const float* gp = aptr + (size_t)j * 32 * 512 + kt * 64;
      areg[j][0] = *(const float4*)gp;
      areg[j][1] = *(const float4*)(gp + 4);
    }
    if (do_k2) {
      const float* csp = colsum + kt * 64 + ac * 8;
      cs0 = *(const float4*)csp;
      cs1 = *(const float4*)(csp + 4);
    }
  };
  auto issue_w = [&](int kt, int buf) {
    const int kbase = kt * 64;
#pragma unroll
    for (int j = 0; j < 4; ++j) {
      int r = wave * 32 + j * 8 + wlr;
      int ldsrow = (wave * 32 + j * 8) * 64;
      size_t goff = (size_t)(col0 + r) * 512 + kbase + cswz * 8;
      async16(W + goff, Wb + buf * 8192 + ldsrow);
    }
  };
  auto write_a = [&](int kt) {
#pragma unroll
    for (int j = 0; j < 4; ++j) {
      union { _Float16 h[8]; uint4 u; } pk;
      float4 lo = areg[j][0], hi = areg[j][1];
      pk.h[0] = (_Float16)lo.x; pk.h[1] = (_Float16)lo.y;
      pk.h[2] = (_Float16)lo.z; pk.h[3] = (_Float16)lo.w;
      pk.h[4] = (_Float16)hi.x; pk.h[5] = (_Float16)hi.y;
      pk.h[6] = (_Float16)hi.z; pk.h[7] = (_Float16)hi.w;
      *(uint4*)&Ah[(ar0 + 32 * j) * 64 + aslot * 8] = pk.u;
    }
    if (do_k2) {
#pragma unroll
      for (int j = 0; j < 4; ++j) {
        float4 lo = areg[j][0], hi = areg[j][1];
        k2p[j] += lo.x * cs0.x + lo.y * cs0.y + lo.z * cs0.z + lo.w * cs0.w +
                  hi.x * cs1.x + hi.y * cs1.y + hi.z * cs1.z + hi.w * cs1.w;
      }
    }
  };

  // prologue: tile 0
  issue_a(0);
  issue_w(0, 0);
  write_a(0);       // counted vmcnt for areg; W(0) stays in flight
  __syncthreads();  // drains W(0), publishes Ah(0)

  for (int kt = 0; kt < 8; ++kt) {
    const int p = kt & 1;
    if (kt < 7) {
      issue_a(kt + 1);         // HBM/L2 latency hides under the MFMAs below
      issue_w(kt + 1, p ^ 1);  // lands in the other W buffer meanwhile
    }
#pragma unroll
    for (int k0 = 0; k0 < 64; k0 += 32) {
      const int cb = (k0 >> 3) + q;
      f16x8 af[4], bf[4];
#pragma unroll
      for (int mi = 0; mi < 4; ++mi) {
        int ra = wm + mi * 16 + rr;
        af[mi] = *(const f16x8*)&Ah[ra * 64 + (cb ^ (ra & 7)) * 8];
      }
#pragma unroll
      for (int ni = 0; ni < 4; ++ni) {
        int rw = wn + ni * 16 + rr;
        int slot = cb ^ (rw & 7);
        bf[ni] = *(const f16x8*)&Wb[p * 8192 + rw * 64 + slot * 8];
      }
      __builtin_amdgcn_s_setprio(1);
#pragma unroll
      for (int mi = 0; mi < 4; ++mi)
#pragma unroll
        for (int ni = 0; ni < 4; ++ni)
          acc[mi][ni] =
              __builtin_amdgcn_mfma_f32_16x16x32_f16(af[mi], bf[ni], acc[mi][ni], 0, 0, 0);
      __builtin_amdgcn_s_setprio(0);
    }
    if (kt < 7) {
      __syncthreads();   // all waves done reading Ah(kt); drains areg + W(kt+1)
      write_a(kt + 1);   // cvt + ds_write + fused k2 dot
      __syncthreads();   // publish Ah(kt+1); Wb[p^1] ready
    }
  }

  const int col = lane & 15, rq = (lane >> 4) * 4;

  if (pass == 0) {
    if (do_k2) {
#pragma unroll
      for (int j = 0; j < 4; ++j) {
        float s = k2p[j];
        s += __shfl_xor(s, 1, 8);
        s += __shfl_xor(s, 2, 8);
        s += __shfl_xor(s, 4, 8);
        if (ac == 0) k2sum[row0 + ar0 + 32 * j] = s;
      }
    }
    // K1: natural [n][e] layout
#pragma unroll
    for (int mi = 0; mi < 4; ++mi)
#pragma unroll
      for (int ni = 0; ni < 4; ++ni)
#pragma unroll
        for (int r = 0; r < 4; ++r) {
          size_t m = row0 + wm + mi * 16 + rq + r;
          size_t e = col0 + wn + ni * 16 + col;
          K1[m * 512 + e] = (_Float16)acc[mi][ni][r];
        }
  } else {
    // V transposed: frags -> swizzled 32 KB LDS tile (S[0..16384)) -> 256B
    // stores. Barrier first: other waves may still be reading Ah/Wb in kt=7.
    __syncthreads();
    _Float16* Vts = S;  // 128 e-rows x 128 n
#pragma unroll
    for (int mi = 0; mi < 4; ++mi)
#pragma unroll
      for (int ni = 0; ni < 4; ++ni) {
        int n0 = wm + mi * 16 + rq;
        int el = wn + ni * 16 + col;
        int cn = n0 >> 3, half = (n0 >> 2) & 1;
        int slot = cn ^ (el & 7);
        union { _Float16 h[4]; unsigned long long u; } pk;
#pragma unroll
        for (int r = 0; r < 4; ++r) pk.h[r] = (_Float16)acc[mi][ni][r];
        *(unsigned long long*)&Vts[el * 128 + slot * 8 + half * 4] = pk.u;
      }
    __syncthreads();
    const int nbase = row0 & 511;
#pragma unroll
    for (int i = 0; i < 8; ++i) {
      int f = tid + i * 256;
      int el = f >> 4, c16 = f & 15;
      int slot = c16 ^ (el & 7);
      uint4 val = *(const uint4*)&Vts[el * 128 + slot * 8];
      *(uint4*)(Vt + (size_t)b * 262144 + (size_t)(col0 + el) * 512 + nbase + c16 * 8) = val;
    }
  }
}

// ---------------- attention: one block per (b,h), all-MFMA -----------------
// R7 structure + V-half-0 prefetch hidden under softmax + T5 setprio around
// MFMA clusters (independent blocks -> wave phase diversity, m191 regime).
__global__ __launch_bounds__(256) void attn_kernel(
    const float* __restrict__ Q1, const _Float16* __restrict__ K1,
    const _Float16* __restrict__ Vt, const int* __restrict__ mask,
    float* __restrict__ heads) {
  const int bid = blockIdx.x;  // 512
  const int b = bid >> 3, h = bid & 7;
  const int tid = threadIdx.x, wave = tid >> 6, lane = tid & 63;
  const int q = lane >> 4, cl = lane & 15;

  __shared__ __align__(16) _Float16 kt[256 * 64];  // 32KB: K-half or Vt-half
  __shared__ __align__(16) _Float16 P[16][520];    // unnormalized probs, f16
  __shared__ float red[4][8];

  f16x8 af[2];
  {
    const float* qp = Q1 + (size_t)(b * 8 + (cl & 7)) * 512 + h * 64 + q * 8;
#pragma unroll
    for (int s = 0; s < 2; ++s) {
      float4 l0 = *(const float4*)(qp + s * 32);
      float4 l1 = *(const float4*)(qp + s * 32 + 4);
      af[s][0] = (_Float16)l0.x; af[s][1] = (_Float16)l0.y;
      af[s][2] = (_Float16)l0.z; af[s][3] = (_Float16)l0.w;
      af[s][4] = (_Float16)l1.x; af[s][5] = (_Float16)l1.y;
      af[s][6] = (_Float16)l1.z; af[s][7] = (_Float16)l1.w;
    }
  }

  // ---- QK^T ----
  f32x4 acc[8] = {};
  const _Float16* Kb = K1 + (size_t)b * 262144 + h * 64;
  for (int h2 = 0; h2 < 2; ++h2) {
#pragma unroll
    for (int j = 0; j < 8; ++j) {
      int r = wave * 64 + j * 8 + (lane >> 3);
      int cg = (lane & 7) ^ (r & 7);
      async16(Kb + (size_t)(h2 * 256 + r) * 512 + cg * 8, &kt[(wave * 64 + j * 8) * 64]);
    }
    __syncthreads();
    __builtin_amdgcn_s_setprio(1);
#pragma unroll
    for (int tt = 0; tt < 4; ++tt) {
      int rn = wave * 64 + tt * 16 + cl;
#pragma unroll
      for (int s = 0; s < 2; ++s) {
        int slot = (s * 4 + q) ^ (cl & 7);
        f16x8 bf = *(const f16x8*)&kt[rn * 64 + slot * 8];
        acc[h2 * 4 + tt] =
            __builtin_amdgcn_mfma_f32_16x16x32_f16(af[s], bf, acc[h2 * 4 + tt], 0, 0, 0);
      }
    }
    __builtin_amdgcn_s_setprio(0);
    __syncthreads();
  }

  // ---- prefetch V half 0 into kt (hidden under softmax) ----
  const _Float16* Vb = Vt + (size_t)b * 262144 + (size_t)h * 64 * 512;
#pragma unroll
  for (int j = 0; j < 8; ++j) {
    int r = wave * 16 + j * 2 + (lane >> 5);
    int cg = (lane & 31) ^ (r & 7);
    async16(Vb + (size_t)r * 512 + cg * 8, &kt[(wave * 16 + j * 2) * 256]);
  }

  // ---- softmax (rows c = q*4+r, valid q<2) ----
  float gmax[4], rsum[4];
  if (q < 2) {
    float mx[4] = {-3e38f, -3e38f, -3e38f, -3e38f};
#pragma unroll
    for (int t = 0; t < 8; ++t) {
      int n = (t >> 2) * 256 + wave * 64 + (t & 3) * 16 + cl;
#pragma unroll
      for (int r = 0; r < 4; ++r) {
        int c = q * 4 + r;
        float x = mask[(size_t)(b * 8 + c) * 512 + n] ? -1e9f : acc[t][r] * 0.125f;
        acc[t][r] = x;
        mx[r] = fmaxf(mx[r], x);
      }
    }
#pragma unroll
    for (int off = 1; off < 16; off <<= 1)
#pragma unroll
      for (int r = 0; r < 4; ++r) mx[r] = fmaxf(mx[r], __shfl_xor(mx[r], off, 64));
    if (cl == 0)
#pragma unroll
      for (int r = 0; r < 4; ++r) red[wave][q * 4 + r] = mx[r];
  }
  __syncthreads();
  if (q < 2) {
#pragma unroll
    for (int r = 0; r < 4; ++r) {
      int c = q * 4 + r;
      gmax[r] = fmaxf(fmaxf(red[0][c], red[1][c]), fmaxf(red[2][c], red[3][c]));
    }
  }
  __syncthreads();
  if (q < 2) {
#pragma unroll
    for (int r = 0; r < 4; ++r) rsum[r] = 0.f;
#pragma unroll
    for (int t = 0; t < 8; ++t) {
      int n = (t >> 2) * 256 + wave * 64 + (t & 3) * 16 + cl;
#pragma unroll
      for (int r = 0; r < 4; ++r) {
        float e = __expf(acc[t][r] - gmax[r]);
        rsum[r] += e;
        P[q * 4 + r][n] = (_Float16)e;
      }
    }
#pragma unroll
    for (int off = 1; off < 16; off <<= 1)
#pragma unroll
      for (int r = 0; r < 4; ++r) rsum[r] += __shfl_xor(rsum[r], off, 64);
    if (cl == 0)
#pragma unroll
      for (int r = 0; r < 4; ++r) red[wave][q * 4 + r] = rsum[r];
  }
  __syncthreads();  // also drains the V half-0 prefetch

  // ---- PV ----
  f32x4 pacc = {};
  const int rn = wave * 16 + cl;
  // half 0: already staged
  __builtin_amdgcn_s_setprio(1);
#pragma unroll
  for (int sl = 0; sl < 8; ++sl) {
    int slot = (sl * 4 + q) ^ (cl & 7);
    f16x8 bf = *(const f16x8*)&kt[rn * 256 + slot * 8];
    f16x8 pa = *(const f16x8*)&P[cl][sl * 32 + q * 8];
    pacc = __builtin_amdgcn_mfma_f32_16x16x32_f16(pa, bf, pacc, 0, 0, 0);
  }
  __builtin_amdgcn_s_setprio(0);
  __syncthreads();
  // half 1: stage + consume
#pragma unroll
  for (int j = 0; j < 8; ++j) {
    int r = wave * 16 + j * 2 + (lane >> 5);
    int cg = (lane & 31) ^ (r & 7);
    async16(Vb + (size_t)r * 512 + 256 + cg * 8, &kt[(wave * 16 + j * 2) * 256]);
  }
  __syncthreads();
  __builtin_amdgcn_s_setprio(1);
#pragma unroll
  for (int sl = 0; sl < 8; ++sl) {
    int slot = (sl * 4 + q) ^ (cl & 7);
    f16x8 bf = *(const f16x8*)&kt[rn * 256 + slot * 8];
    f16x8 pa = *(const f16x8*)&P[cl][256 + sl * 32 + q * 8];
    pacc = __builtin_amdgcn_mfma_f32_16x16x32_f16(pa, bf, pacc, 0, 0, 0);
  }
  __builtin_amdgcn_s_setprio(0);

  if (q < 2) {
#pragma unroll
    for (int r = 0; r < 4; ++r) {
      int c = q * 4 + r;
      float inv = 1.f / (red[0][c] + red[1][c] + red[2][c] + red[3][c]);
      heads[(size_t)(b * 8 + c) * 512 + h * 64 + wave * 16 + cl] = pacc[r] * inv;
    }
  }
}

// ---------------- Q3 = heads @ Wout.T, 64x64 tiles, K-split 2 --------------
__global__ __launch_bounds__(256) void gemm_out64(const float* __restrict__ A,
                                                  const float* __restrict__ W,
                                                  float* __restrict__ C) {
  const int mb = blockIdx.x, nb = blockIdx.y, ks = blockIdx.z;
  const int tid = threadIdx.x;
  const int lane = tid & 63, wave = tid >> 6;
  const int wm = (wave >> 1) * 32, wn = (wave & 1) * 32;

  __shared__ __align__(16) _Float16 As[64][40];
  __shared__ __align__(16) _Float16 Ws[64][40];

  f32x4 acc[2][2] = {};
  const int qd = (lane >> 4) * 8, rr = lane & 15;

  for (int kt = 0; kt < 8; ++kt) {
    const int kb = ks * 256 + kt * 32;
#pragma unroll
    for (int f0 = 0; f0 < 2; ++f0) {
      int f = tid + f0 * 256;
      int r = f >> 3, c4 = (f & 7) * 4;
      float4 a = *(const float4*)(A + (size_t)(mb * 64 + r) * 512 + kb + c4);
      float4 w = *(const float4*)(W + (size_t)(nb * 64 + r) * 512 + kb + c4);
      As[r][c4 + 0] = (_Float16)a.x; As[r][c4 + 1] = (_Float16)a.y;
      As[r][c4 + 2] = (_Float16)a.z; As[r][c4 + 3] = (_Float16)a.w;
      Ws[r][c4 + 0] = (_Float16)w.x; Ws[r][c4 + 1] = (_Float16)w.y;
      Ws[r][c4 + 2] = (_Float16)w.z; Ws[r][c4 + 3] = (_Float16)w.w;
    }
    __syncthreads();
    f16x8 af[2], bfr[2];
#pragma unroll
    for (int mi = 0; mi < 2; ++mi) af[mi] = *(const f16x8*)&As[wm + mi * 16 + rr][qd];
#pragma unroll
    for (int ni = 0; ni < 2; ++ni) bfr[ni] = *(const f16x8*)&Ws[wn + ni * 16 + rr][qd];
#pragma unroll
    for (int mi = 0; mi < 2; ++mi)
#pragma unroll
      for (int ni = 0; ni < 2; ++ni)
        acc[mi][ni] =
            __builtin_amdgcn_mfma_f32_16x16x32_f16(af[mi], bfr[ni], acc[mi][ni], 0, 0, 0);
    __syncthreads();
  }

  const int col = lane & 15, rq = (lane >> 4) * 4;
#pragma unroll
  for (int mi = 0; mi < 2; ++mi)
#pragma unroll
    for (int ni = 0; ni < 2; ++ni)
#pragma unroll
      for (int r = 0; r < 4; ++r) {
        int m = mb * 64 + wm + mi * 16 + rq + r;
        int e = nb * 64 + wn + ni * 16 + col;
        atomicAdd(&C[(size_t)m * 512 + e], acc[mi][ni][r]);
      }
}

// ---------------- fused u_scalar + logits ----------------------------------
__global__ __launch_bounds__(256) void logits_u_kernel(
    const float* __restrict__ Q1, const float* __restrict__ v,
    const float* __restrict__ k2s, const int* __restrict__ mask,
    float* __restrict__ out) {
  const int bc = blockIdx.x;
  const int b = bc >> 3;
  const int tid = threadIdx.x;
  const int wave = tid >> 6, lane = tid & 63;

  float p = tanhf(Q1[(size_t)bc * 512 + tid]) * v[tid] +
            tanhf(Q1[(size_t)bc * 512 + tid + 256]) * v[tid + 256];
#pragma unroll
  for (int off = 32; off; off >>= 1) p += __shfl_down(p, off, 64);
  __shared__ float red[4];
  __shared__ float su;
  if (lane == 0) red[wave] = p;
  __syncthreads();
  if (tid == 0) su = red[0] + red[1] + red[2] + red[3];
  __syncthreads();
  const float u = su;

#pragma unroll
  for (int i = 0; i < 2; ++i) {
    int n = tid + i * 256;
    int idx = bc * 512 + n;
    out[idx] = mask[idx] ? -1e9f
                         : 10.f * tanhf(u * k2s[b * 512 + n] * 0.04419417382415922f);
  }
}

extern "C" void kernel_launch(void* const* d_in, const int* in_sizes, int n_in,
                              void* d_out, int out_size, void* d_ws, size_t ws_size,
                              hipStream_t stream) {
  const float* ne = (const float*)d_in[0];
  const float* ge = (const float*)d_in[1];
  const float* sc = (const float*)d_in[2];
  const int* mask = (const int*)d_in[3];
  const float* Wk1 = (const float*)d_in[4];
  const float* Wv = (const float*)d_in[5];
  const float* Wk2 = (const float*)d_in[6];
  const float* Wqf = (const float*)d_in[7];
  const float* Wout = (const float*)d_in[8];
  const float* Wqs = (const float*)d_in[9];
  const float* v = (const float*)d_in[10];

  float* logits = (float*)d_out;
  float* q3 = (float*)d_out + 262144;

  // ws layout: R4/R7-proven 70.4 MB envelope.
  char* ws = (char*)d_ws;
  _Float16* K1 = (_Float16*)(ws + 0);          // 33,554,432 B  [b][n][e]
  _Float16* Vt = (_Float16*)(ws + 33554432);   // 33,554,432 B  [b][e][n]
  float* Q1 = (float*)(ws + 67108864);         // 1,048,576 B
  float* heads = (float*)(ws + 68157440);      // 1,048,576 B
  float* k2sum = (float*)(ws + 69206016);      // 131,072 B
  float* colsum = (float*)(ws + 69337088);     // 2,048 B
  _Float16* W1h = (_Float16*)(ws + 69339136);  // 524,288 B
  _Float16* W2h = (_Float16*)(ws + 69863424);  // 524,288 B

  hipMemsetAsync(Q1, 0, 1048576, stream);
  hipMemsetAsync(q3, 0, 1048576, stream);
  prep_w<<<272, 256, 0, stream>>>(Wk1, Wv, Wk2, W1h, W2h, colsum);
  q1_mfma_kernel<<<dim3(8, 8, 4), 256, 0, stream>>>(ge, sc, Wqf, Wqs, Q1);
  gemm_kv<<<2048, 256, 0, stream>>>(ne, W1h, W2h, colsum, K1, Vt, k2sum);
  attn_kernel<<<512, 256, 0, stream>>>(Q1, K1, Vt, mask, heads);
  gemm_out64<<<dim3(8, 8, 2), 256, 0, stream>>>(heads, Wout, q3);
  logits_u_kernel<<<512, 256, 0, stream>>>(Q1, v, k2sum, mask, logits);
}

// Round 6
// 204.297 us; speedup vs baseline: 1.1026x; 1.1026x over previous
//
#include <hip/hip_runtime.h>

// Dims fixed by the problem: B=64, C=8, N=512, E=512, H=8, dh=64
// logits out: [B, C*N] = 262144 floats at d_out[0]
// Q3 out:     [B, C, E] = 262144 floats at d_out[262144]

typedef _Float16 f16x8 __attribute__((ext_vector_type(8)));
typedef float f32x4 __attribute__((ext_vector_type(4)));

__device__ __forceinline__ void async16(const void* g, void* l) {
  __builtin_amdgcn_global_load_lds(
      (const __attribute__((address_space(1))) unsigned int*)g,
      (__attribute__((address_space(3))) unsigned int*)l, 16, 0, 0);
}

__device__ __forceinline__ float fast_tanh(float x) {
  float ax = fabsf(x);
  float t = __expf(-2.f * ax);      // ->0 for large ax, saturation-safe
  float r = (1.f - t) / (1.f + t);
  return copysignf(r, x);
}

// ------------- merged: prep (colsum + W->f16) ∥ Q1 GEMM --------------------
// blocks 0..271: prep_w body; blocks 272..527: q1 (flattened 8x8x4).
// Independent work merged into one launch: removes a launch gap and lets the
// tiny memory-bound prep blocks overlap q1's 1-block/CU compute.
__global__ __launch_bounds__(256) void prep_q1(
    const float* __restrict__ Wk1, const float* __restrict__ Wv,
    const float* __restrict__ Wk2, _Float16* __restrict__ W1h,
    _Float16* __restrict__ W2h, float* __restrict__ colsum,
    const float* __restrict__ ge, const float* __restrict__ sc,
    const float* __restrict__ Wqf, const float* __restrict__ Wqs,
    float* __restrict__ Q1) {
  const int bid = blockIdx.x;
  if (bid < 272) {
    if (bid < 16) {
      const int tx = threadIdx.x & 31, ty = threadIdx.x >> 5;
      const int col = bid * 32 + tx;
      float s = 0.f;
#pragma unroll 4
      for (int e = ty * 64; e < ty * 64 + 64; ++e) s += Wk2[e * 512 + col];
      __shared__ float red[8][32];
      red[ty][tx] = s;
      __syncthreads();
      if (ty == 0) {
        float t = 0.f;
#pragma unroll
        for (int g = 0; g < 8; ++g) t += red[g][tx];
        colsum[col] = t;
      }
    } else {
      const int cb = bid - 16;
      const float* src = (cb < 128) ? Wk1 : Wv;
      _Float16* dst = (cb < 128) ? W1h : W2h;
      const size_t off = (size_t)(cb & 127) * 2048 + threadIdx.x * 8;
      float4 a = *(const float4*)(src + off);
      float4 b = *(const float4*)(src + off + 4);
      union { _Float16 h[8]; uint4 u; } pk;
      pk.h[0] = (_Float16)a.x; pk.h[1] = (_Float16)a.y;
      pk.h[2] = (_Float16)a.z; pk.h[3] = (_Float16)a.w;
      pk.h[4] = (_Float16)b.x; pk.h[5] = (_Float16)b.y;
      pk.h[6] = (_Float16)b.z; pk.h[7] = (_Float16)b.w;
      *(uint4*)(dst + off) = pk.u;
    }
    return;
  }

  // ---- Q1 = [ge | sc] @ [Wqf | Wqs].T  (K=1026), 64x64 tiles, ks-split 4
  const int b2 = bid - 272;
  const int mb = b2 & 7, nb = (b2 >> 3) & 7, ks = b2 >> 6;
  const int tid = threadIdx.x;
  const int lane = tid & 63, wave = tid >> 6;
  const int wm = (wave >> 1) * 32, wn = (wave & 1) * 32;

  __shared__ __align__(16) _Float16 As[64][40];
  __shared__ __align__(16) _Float16 Ws[64][40];

  f32x4 acc[2][2] = {};
  const int qd = (lane >> 4) * 8, rr = lane & 15;

  for (int kt = 0; kt < 9; ++kt) {
    const int kb = ks * 288 + kt * 32;
#pragma unroll
    for (int f0 = 0; f0 < 2; ++f0) {
      int f = tid + f0 * 256;
      int r = f >> 3, c4 = (f & 7) * 4;
      int m = mb * 64 + r;
      int e = nb * 64 + r;
#pragma unroll
      for (int j = 0; j < 4; ++j) {
        int k = kb + c4 + j;
        float a = 0.f, w = 0.f;
        if (k < 512) {
          a = ge[(m >> 3) * 512 + k];
          w = Wqf[(size_t)e * 512 + k];
        } else if (k < 1026) {
          a = sc[(size_t)m * 514 + (k - 512)];
          w = Wqs[(size_t)e * 514 + (k - 512)];
        }
        As[r][c4 + j] = (_Float16)a;
        Ws[r][c4 + j] = (_Float16)w;
      }
    }
    __syncthreads();
    f16x8 af[2], bfr[2];
#pragma unroll
    for (int mi = 0; mi < 2; ++mi) af[mi] = *(const f16x8*)&As[wm + mi * 16 + rr][qd];
#pragma unroll
    for (int ni = 0; ni < 2; ++ni) bfr[ni] = *(const f16x8*)&Ws[wn + ni * 16 + rr][qd];
#pragma unroll
    for (int mi = 0; mi < 2; ++mi)
#pragma unroll
      for (int ni = 0; ni < 2; ++ni)
        acc[mi][ni] =
            __builtin_amdgcn_mfma_f32_16x16x32_f16(af[mi], bfr[ni], acc[mi][ni], 0, 0, 0);
    __syncthreads();
  }

  const int col = lane & 15, rq = (lane >> 4) * 4;
#pragma unroll
  for (int mi = 0; mi < 2; ++mi)
#pragma unroll
    for (int ni = 0; ni < 2; ++ni)
#pragma unroll
      for (int r = 0; r < 4; ++r) {
        int m = mb * 64 + wm + mi * 16 + rq + r;
        int e = nb * 64 + wn + ni * 16 + col;
        atomicAdd(&Q1[(size_t)m * 512 + e], acc[mi][ni][r]);
      }
}

// ---------------- fused K1+V GEMM + k2sum; K1 and V-transposed -------------
// R10 structure (best measured: 63 µs): T14 async-stage split + XCD-chunked
// swizzle + dual accumulator (2x compute per staged byte beats +1 block/CU:
// R11's split-pass at 3 blocks/CU regressed to 72 µs). 2 blocks/CU.
__global__ __launch_bounds__(256, 2) void gemm_kv(
    const float* __restrict__ A, const _Float16* __restrict__ W1,
    const _Float16* __restrict__ W2, const float* __restrict__ colsum,
    _Float16* __restrict__ K1, _Float16* __restrict__ Vt,
    float* __restrict__ k2sum) {
  const int flat = (int)(blockIdx.y * 4 + blockIdx.x);  // dispatch-linear id
  const int work = (flat & 7) * 128 + (flat >> 3);      // bijective, 1024%8==0
  const int nb = work & 3;
  const int mb = work >> 2;
  const int tid = threadIdx.x, lane = tid & 63, wave = tid >> 6;
  const int wm = (wave >> 1) * 64, wn = (wave & 1) * 64;
  const int row0 = mb * 128, col0 = nb * 128;
  const int b = mb >> 2;

  __shared__ __align__(16) _Float16 Ah[128 * 64];        // 16 KB f16, swizzled
  __shared__ __align__(16) _Float16 Wb[2][2][128 * 64];  // 64 KB, double-buffered

  f32x4 acc1[4][4] = {}, acc2[4][4] = {};
  float k2p[4] = {0.f, 0.f, 0.f, 0.f};
  const int q = lane >> 4, rr = lane & 15;
  const int wlr = lane >> 3, wlc = lane & 7;
  const int cswz = wlc ^ wlr;  // W chunk swizzle (8 chunks of 8 f16 per row)

  // A staging geometry: thread owns rows ar0+32j (j=0..3), 8-half chunk ac.
  const int ar0 = tid >> 3, ac = tid & 7;
  const float* aptr = A + (size_t)(row0 + ar0) * 512 + ac * 8;
  const int aslot = ac ^ (ar0 & 7);  // (row&7)==(ar0&7) for all j (32j = 0 mod 8)

  float4 areg[4][2];
  float4 cs0, cs1;  // colsum slice for the NEXT write_a (hoisted off crit path)

  auto issue_a = [&](int kt) {
#pragma unroll
    for (int j = 0; j < 4; ++j) {
      const float* gp = aptr + (size_t)j * 32 * 512 + kt * 64;
      areg[j][0] = *(const float4*)gp;
      areg[j][1] = *(const float4*)(gp + 4);
    }
    if (nb == 0) {  // colsum for this kt, consumed by write_a(kt)
      const float* csp = colsum + kt * 64 + ac * 8;
      cs0 = *(const float4*)csp;
      cs1 = *(const float4*)(csp + 4);
    }
  };
  auto issue_w = [&](int kt, int buf) {
    const int kbase = kt * 64;
#pragma unroll
    for (int j = 0; j < 4; ++j) {
      int r = wave * 32 + j * 8 + wlr;
      int ldsrow = (wave * 32 + j * 8) * 64;
      size_t goff = (size_t)(col0 + r) * 512 + kbase + cswz * 8;
      async16(W1 + goff, &Wb[buf][0][ldsrow]);
      async16(W2 + goff, &Wb[buf][1][ldsrow]);
    }
  };
  auto write_a = [&](int kt) {
#pragma unroll
    for (int j = 0; j < 4; ++j) {
      union { _Float16 h[8]; uint4 u; } pk;
      float4 lo = areg[j][0], hi = areg[j][1];
      pk.h[0] = (_Float16)lo.x; pk.h[1] = (_Float16)lo.y;
      pk.h[2] = (_Float16)lo.z; pk.h[3] = (_Float16)lo.w;
      pk.h[4] = (_Float16)hi.x; pk.h[5] = (_Float16)hi.y;
      pk.h[6] = (_Float16)hi.z; pk.h[7] = (_Float16)hi.w;
      *(uint4*)&Ah[(ar0 + 32 * j) * 64 + aslot * 8] = pk.u;
    }
    if (nb == 0) {  // fused k2sum from fp32 regs (full precision)
#pragma unroll
      for (int j = 0; j < 4; ++j) {
        float4 lo = areg[j][0], hi = areg[j][1];
        k2p[j] += lo.x * cs0.x + lo.y * cs0.y + lo.z * cs0.z + lo.w * cs0.w +
                  hi.x * cs1.x + hi.y * cs1.y + hi.z * cs1.z + hi.w * cs1.w;
      }
    }
  };

  // prologue: tile 0
  issue_a(0);
  issue_w(0, 0);
  write_a(0);       // compiler-counted vmcnt for areg; W(0) stays in flight
  __syncthreads();  // drains W(0), publishes Ah(0)

  for (int kt = 0; kt < 8; ++kt) {
    const int p = kt & 1;
    if (kt < 7) {
      issue_a(kt + 1);         // HBM latency hides under the MFMAs below
      issue_w(kt + 1, p ^ 1);  // lands in the other W buffer meanwhile
    }
#pragma unroll
    for (int k0 = 0; k0 < 64; k0 += 32) {
      const int cb = (k0 >> 3) + q;
      f16x8 af[4], b1[4], b2[4];
#pragma unroll
      for (int mi = 0; mi < 4; ++mi) {
        int ra = wm + mi * 16 + rr;
        af[mi] = *(const f16x8*)&Ah[ra * 64 + (cb ^ (ra & 7)) * 8];
      }
#pragma unroll
      for (int ni = 0; ni < 4; ++ni) {
        int rw = wn + ni * 16 + rr;
        int slot = cb ^ (rw & 7);
        b1[ni] = *(const f16x8*)&Wb[p][0][rw * 64 + slot * 8];
        b2[ni] = *(const f16x8*)&Wb[p][1][rw * 64 + slot * 8];
      }
      __builtin_amdgcn_s_setprio(1);
#pragma unroll
      for (int mi = 0; mi < 4; ++mi)
#pragma unroll
        for (int ni = 0; ni < 4; ++ni) {
          acc1[mi][ni] =
              __builtin_amdgcn_mfma_f32_16x16x32_f16(af[mi], b1[ni], acc1[mi][ni], 0, 0, 0);
          acc2[mi][ni] =
              __builtin_amdgcn_mfma_f32_16x16x32_f16(af[mi], b2[ni], acc2[mi][ni], 0, 0, 0);
        }
      __builtin_amdgcn_s_setprio(0);
    }
    if (kt < 7) {
      __syncthreads();   // all waves done reading Ah(kt); drains areg + W(kt+1)
      write_a(kt + 1);   // cvt + ds_write + fused k2 dot (colsum already in regs)
      __syncthreads();   // publish Ah(kt+1); Wb[p^1] ready
    }
  }

  if (nb == 0) {
#pragma unroll
    for (int j = 0; j < 4; ++j) {
      float s = k2p[j];
      s += __shfl_xor(s, 1, 8);
      s += __shfl_xor(s, 2, 8);
      s += __shfl_xor(s, 4, 8);
      if (ac == 0) k2sum[row0 + (tid >> 3) + 32 * j] = s;
    }
  }

  const int col = lane & 15, rq = (lane >> 4) * 4;
  // K1: natural [n][e] layout
#pragma unroll
  for (int mi = 0; mi < 4; ++mi)
#pragma unroll
    for (int ni = 0; ni < 4; ++ni)
#pragma unroll
      for (int r = 0; r < 4; ++r) {
        size_t m = row0 + wm + mi * 16 + rq + r;
        size_t e = col0 + wn + ni * 16 + col;
        K1[m * 512 + e] = (_Float16)acc1[mi][ni][r];
      }

  // V transposed: frags -> swizzled LDS tile (reuse Wb[0], 32 KB) -> 256B
  // stores. Safe: compute(7) reads only Wb[1]+Ah; Wb[0] last read at kt=6,
  // behind kt=6's trailing barrier.
  _Float16* Vts = &Wb[0][0][0];  // 128 e-rows x 128 n
#pragma unroll
  for (int mi = 0; mi < 4; ++mi)
#pragma unroll
    for (int ni = 0; ni < 4; ++ni) {
      int n0 = wm + mi * 16 + rq;
      int el = wn + ni * 16 + col;
      int cn = n0 >> 3, half = (n0 >> 2) & 1;
      int slot = cn ^ (el & 7);
      union { _Float16 h[4]; unsigned long long u; } pk;
#pragma unroll
      for (int r = 0; r < 4; ++r) pk.h[r] = (_Float16)acc2[mi][ni][r];
      *(unsigned long long*)&Vts[el * 128 + slot * 8 + half * 4] = pk.u;
    }
  __syncthreads();
  const int nbase = row0 & 511;
#pragma unroll
  for (int i = 0; i < 8; ++i) {
    int f = tid + i * 256;
    int el = f >> 4, c16 = f & 15;
    int slot = c16 ^ (el & 7);
    uint4 val = *(const uint4*)&Vts[el * 128 + slot * 8];
    *(uint4*)(Vt + (size_t)b * 262144 + (size_t)(col0 + el) * 512 + nbase + c16 * 8) = val;
  }
}

// ---------------- attention: one block per (b,h), all-MFMA -----------------
// R7 structure + V-half-0 prefetch hidden under softmax + T5 setprio around
// MFMA clusters (independent blocks -> wave phase diversity, m191 regime).
__global__ __launch_bounds__(256) void attn_kernel(
    const float* __restrict__ Q1, const _Float16* __restrict__ K1,
    const _Float16* __restrict__ Vt, const int* __restrict__ mask,
    float* __restrict__ heads) {
  const int bid = blockIdx.x;  // 512
  const int b = bid >> 3, h = bid & 7;
  const int tid = threadIdx.x, wave = tid >> 6, lane = tid & 63;
  const int q = lane >> 4, cl = lane & 15;

  __shared__ __align__(16) _Float16 kt[256 * 64];  // 32KB: K-half or Vt-half
  __shared__ __align__(16) _Float16 P[16][520];    // unnormalized probs, f16
  __shared__ float red[4][8];

  f16x8 af[2];
  {
    const float* qp = Q1 + (size_t)(b * 8 + (cl & 7)) * 512 + h * 64 + q * 8;
#pragma unroll
    for (int s = 0; s < 2; ++s) {
      float4 l0 = *(const float4*)(qp + s * 32);
      float4 l1 = *(const float4*)(qp + s * 32 + 4);
      af[s][0] = (_Float16)l0.x; af[s][1] = (_Float16)l0.y;
      af[s][2] = (_Float16)l0.z; af[s][3] = (_Float16)l0.w;
      af[s][4] = (_Float16)l1.x; af[s][5] = (_Float16)l1.y;
      af[s][6] = (_Float16)l1.z; af[s][7] = (_Float16)l1.w;
    }
  }

  // ---- QK^T ----
  f32x4 acc[8] = {};
  const _Float16* Kb = K1 + (size_t)b * 262144 + h * 64;
  for (int h2 = 0; h2 < 2; ++h2) {
#pragma unroll
    for (int j = 0; j < 8; ++j) {
      int r = wave * 64 + j * 8 + (lane >> 3);
      int cg = (lane & 7) ^ (r & 7);
      async16(Kb + (size_t)(h2 * 256 + r) * 512 + cg * 8, &kt[(wave * 64 + j * 8) * 64]);
    }
    __syncthreads();
    __builtin_amdgcn_s_setprio(1);
#pragma unroll
    for (int tt = 0; tt < 4; ++tt) {
      int rn = wave * 64 + tt * 16 + cl;
#pragma unroll
      for (int s = 0; s < 2; ++s) {
        int slot = (s * 4 + q) ^ (cl & 7);
        f16x8 bf = *(const f16x8*)&kt[rn * 64 + slot * 8];
        acc[h2 * 4 + tt] =
            __builtin_amdgcn_mfma_f32_16x16x32_f16(af[s], bf, acc[h2 * 4 + tt], 0, 0, 0);
      }
    }
    __builtin_amdgcn_s_setprio(0);
    __syncthreads();
  }

  // ---- prefetch V half 0 into kt (hidden under softmax) ----
  const _Float16* Vb = Vt + (size_t)b * 262144 + (size_t)h * 64 * 512;
#pragma unroll
  for (int j = 0; j < 8; ++j) {
    int r = wave * 16 + j * 2 + (lane >> 5);
    int cg = (lane & 31) ^ (r & 7);
    async16(Vb + (size_t)r * 512 + cg * 8, &kt[(wave * 16 + j * 2) * 256]);
  }

  // ---- softmax (rows c = q*4+r, valid q<2) ----
  float gmax[4], rsum[4];
  if (q < 2) {
    float mx[4] = {-3e38f, -3e38f, -3e38f, -3e38f};
#pragma unroll
    for (int t = 0; t < 8; ++t) {
      int n = (t >> 2) * 256 + wave * 64 + (t & 3) * 16 + cl;
#pragma unroll
      for (int r = 0; r < 4; ++r) {
        int c = q * 4 + r;
        float x = mask[(size_t)(b * 8 + c) * 512 + n] ? -1e9f : acc[t][r] * 0.125f;
        acc[t][r] = x;
        mx[r] = fmaxf(mx[r], x);
      }
    }
#pragma unroll
    for (int off = 1; off < 16; off <<= 1)
#pragma unroll
      for (int r = 0; r < 4; ++r) mx[r] = fmaxf(mx[r], __shfl_xor(mx[r], off, 64));
    if (cl == 0)
#pragma unroll
      for (int r = 0; r < 4; ++r) red[wave][q * 4 + r] = mx[r];
  }
  __syncthreads();
  if (q < 2) {
#pragma unroll
    for (int r = 0; r < 4; ++r) {
      int c = q * 4 + r;
      gmax[r] = fmaxf(fmaxf(red[0][c], red[1][c]), fmaxf(red[2][c], red[3][c]));
    }
  }
  __syncthreads();
  if (q < 2) {
#pragma unroll
    for (int r = 0; r < 4; ++r) rsum[r] = 0.f;
#pragma unroll
    for (int t = 0; t < 8; ++t) {
      int n = (t >> 2) * 256 + wave * 64 + (t & 3) * 16 + cl;
#pragma unroll
      for (int r = 0; r < 4; ++r) {
        float e = __expf(acc[t][r] - gmax[r]);
        rsum[r] += e;
        P[q * 4 + r][n] = (_Float16)e;
      }
    }
#pragma unroll
    for (int off = 1; off < 16; off <<= 1)
#pragma unroll
      for (int r = 0; r < 4; ++r) rsum[r] += __shfl_xor(rsum[r], off, 64);
    if (cl == 0)
#pragma unroll
      for (int r = 0; r < 4; ++r) red[wave][q * 4 + r] = rsum[r];
  }
  __syncthreads();  // also drains the V half-0 prefetch

  // ---- PV ----
  f32x4 pacc = {};
  const int rn = wave * 16 + cl;
  // half 0: already staged
  __builtin_amdgcn_s_setprio(1);
#pragma unroll
  for (int sl = 0; sl < 8; ++sl) {
    int slot = (sl * 4 + q) ^ (cl & 7);
    f16x8 bf = *(const f16x8*)&kt[rn * 256 + slot * 8];
    f16x8 pa = *(const f16x8*)&P[cl][sl * 32 + q * 8];
    pacc = __builtin_amdgcn_mfma_f32_16x16x32_f16(pa, bf, pacc, 0, 0, 0);
  }
  __builtin_amdgcn_s_setprio(0);
  __syncthreads();
  // half 1: stage + consume
#pragma unroll
  for (int j = 0; j < 8; ++j) {
    int r = wave * 16 + j * 2 + (lane >> 5);
    int cg = (lane & 31) ^ (r & 7);
    async16(Vb + (size_t)r * 512 + 256 + cg * 8, &kt[(wave * 16 + j * 2) * 256]);
  }
  __syncthreads();
  __builtin_amdgcn_s_setprio(1);
#pragma unroll
  for (int sl = 0; sl < 8; ++sl) {
    int slot = (sl * 4 + q) ^ (cl & 7);
    f16x8 bf = *(const f16x8*)&kt[rn * 256 + slot * 8];
    f16x8 pa = *(const f16x8*)&P[cl][256 + sl * 32 + q * 8];
    pacc = __builtin_amdgcn_mfma_f32_16x16x32_f16(pa, bf, pacc, 0, 0, 0);
  }
  __builtin_amdgcn_s_setprio(0);

  if (q < 2) {
#pragma unroll
    for (int r = 0; r < 4; ++r) {
      int c = q * 4 + r;
      float inv = 1.f / (red[0][c] + red[1][c] + red[2][c] + red[3][c]);
      heads[(size_t)(b * 8 + c) * 512 + h * 64 + wave * 16 + cl] = pacc[r] * inv;
    }
  }
}

// ------------- merged: Q3 = heads @ Wout.T ∥ u+logits ----------------------
// blocks 0..255: gemm_out 64x64 tiles, K-split 4 (1 block/CU alone);
// blocks 256..767: logits. Independent work — the memory-bound logits blocks
// fill the CUs the 256-block GEMM leaves under-occupied, and one launch gap
// disappears.
__global__ __launch_bounds__(256) void out_logits(
    const float* __restrict__ A, const float* __restrict__ W,
    float* __restrict__ C, const float* __restrict__ Q1,
    const float* __restrict__ v, const float* __restrict__ k2s,
    const int* __restrict__ mask, float* __restrict__ out) {
  const int bid = blockIdx.x;
  if (bid < 256) {
    const int mb = bid & 7, nb = (bid >> 3) & 7, ks = bid >> 6;
    const int tid = threadIdx.x;
    const int lane = tid & 63, wave = tid >> 6;
    const int wm = (wave >> 1) * 32, wn = (wave & 1) * 32;

    __shared__ __align__(16) _Float16 As[64][40];
    __shared__ __align__(16) _Float16 Ws[64][40];

    f32x4 acc[2][2] = {};
    const int qd = (lane >> 4) * 8, rr = lane & 15;

    for (int kt = 0; kt < 4; ++kt) {
      const int kb = ks * 128 + kt * 32;
#pragma unroll
      for (int f0 = 0; f0 < 2; ++f0) {
        int f = tid + f0 * 256;
        int r = f >> 3, c4 = (f & 7) * 4;
        float4 a = *(const float4*)(A + (size_t)(mb * 64 + r) * 512 + kb + c4);
        float4 w = *(const float4*)(W + (size_t)(nb * 64 + r) * 512 + kb + c4);
        As[r][c4 + 0] = (_Float16)a.x; As[r][c4 + 1] = (_Float16)a.y;
        As[r][c4 + 2] = (_Float16)a.z; As[r][c4 + 3] = (_Float16)a.w;
        Ws[r][c4 + 0] = (_Float16)w.x; Ws[r][c4 + 1] = (_Float16)w.y;
        Ws[r][c4 + 2] = (_Float16)w.z; Ws[r][c4 + 3] = (_Float16)w.w;
      }
      __syncthreads();
      f16x8 af[2], bfr[2];
#pragma unroll
      for (int mi = 0; mi < 2; ++mi) af[mi] = *(const f16x8*)&As[wm + mi * 16 + rr][qd];
#pragma unroll
      for (int ni = 0; ni < 2; ++ni) bfr[ni] = *(const f16x8*)&Ws[wn + ni * 16 + rr][qd];
#pragma unroll
      for (int mi = 0; mi < 2; ++mi)
#pragma unroll
        for (int ni = 0; ni < 2; ++ni)
          acc[mi][ni] =
              __builtin_amdgcn_mfma_f32_16x16x32_f16(af[mi], bfr[ni], acc[mi][ni], 0, 0, 0);
      __syncthreads();
    }

    const int col = lane & 15, rq = (lane >> 4) * 4;
#pragma unroll
    for (int mi = 0; mi < 2; ++mi)
#pragma unroll
      for (int ni = 0; ni < 2; ++ni)
#pragma unroll
        for (int r = 0; r < 4; ++r) {
          int m = mb * 64 + wm + mi * 16 + rq + r;
          int e = nb * 64 + wn + ni * 16 + col;
          atomicAdd(&C[(size_t)m * 512 + e], acc[mi][ni][r]);
        }
    return;
  }

  // ---- logits: u = sum tanh(Q1)*v; out = clip*tanh(u*k2sum/sqrt(E)) ----
  const int bc = bid - 256;
  const int b = bc >> 3;
  const int tid = threadIdx.x;
  const int wave = tid >> 6, lane = tid & 63;

  float p = fast_tanh(Q1[(size_t)bc * 512 + tid]) * v[tid] +
            fast_tanh(Q1[(size_t)bc * 512 + tid + 256]) * v[tid + 256];
#pragma unroll
  for (int off = 32; off; off >>= 1) p += __shfl_down(p, off, 64);
  __shared__ float red[4];
  __shared__ float su;
  if (lane == 0) red[wave] = p;
  __syncthreads();
  if (tid == 0) su = red[0] + red[1] + red[2] + red[3];
  __syncthreads();
  const float u = su;

#pragma unroll
  for (int i = 0; i < 2; ++i) {
    int n = tid + i * 256;
    int idx = bc * 512 + n;
    out[idx] = mask[idx] ? -1e9f
                         : 10.f * fast_tanh(u * k2s[b * 512 + n] * 0.04419417382415922f);
  }
}

extern "C" void kernel_launch(void* const* d_in, const int* in_sizes, int n_in,
                              void* d_out, int out_size, void* d_ws, size_t ws_size,
                              hipStream_t stream) {
  const float* ne = (const float*)d_in[0];
  const float* ge = (const float*)d_in[1];
  const float* sc = (const float*)d_in[2];
  const int* mask = (const int*)d_in[3];
  const float* Wk1 = (const float*)d_in[4];
  const float* Wv = (const float*)d_in[5];
  const float* Wk2 = (const float*)d_in[6];
  const float* Wqf = (const float*)d_in[7];
  const float* Wout = (const float*)d_in[8];
  const float* Wqs = (const float*)d_in[9];
  const float* v = (const float*)d_in[10];

  float* logits = (float*)d_out;
  float* q3 = (float*)d_out + 262144;

  // ws layout: R4/R7-proven 70.4 MB envelope.
  char* ws = (char*)d_ws;
  _Float16* K1 = (_Float16*)(ws + 0);          // 33,554,432 B  [b][n][e]
  _Float16* Vt = (_Float16*)(ws + 33554432);   // 33,554,432 B  [b][e][n]
  float* Q1 = (float*)(ws + 67108864);         // 1,048,576 B
  float* heads = (float*)(ws + 68157440);      // 1,048,576 B
  float* k2sum = (float*)(ws + 69206016);      // 131,072 B
  float* colsum = (float*)(ws + 69337088);     // 2,048 B
  _Float16* W1h = (_Float16*)(ws + 69339136);  // 524,288 B
  _Float16* W2h = (_Float16*)(ws + 69863424);  // 524,288 B

  hipMemsetAsync(Q1, 0, 1048576, stream);
  hipMemsetAsync(q3, 0, 1048576, stream);
  prep_q1<<<528, 256, 0, stream>>>(Wk1, Wv, Wk2, W1h, W2h, colsum,
                                   ge, sc, Wqf, Wqs, Q1);
  gemm_kv<<<dim3(4, 256), 256, 0, stream>>>(ne, W1h, W2h, colsum, K1, Vt, k2sum);
  attn_kernel<<<512, 256, 0, stream>>>(Q1, K1, Vt, mask, heads);
  out_logits<<<768, 256, 0, stream>>>(heads, Wout, q3, Q1, v, k2sum, mask, logits);
}